// Round 7
// baseline (177.485 us; speedup 1.0000x reference)
//
#include <hip/hip_runtime.h>

#define IMG 512
#define NPLANES 48            // 16*3
#define TW 64                 // output tile width
#define TH 16                 // output tile height (was 32; shrunk to fit raw staging in LDS)
#define RD 5
#define KW 11
#define VC (TW + 2*RD)        // 74 columns of vertical sums
#define RROWS (TH + 2*RD)     // 26 raw rows staged
#define RSTR 76               // raw LDS row stride (76 floats = 304B, 16B-aligned)
#define GPR 38                // float2 granules per staged row (76 cols)
#define NGRAN (RROWS*GPR)     // 988 staging granules per image
#define PRW (2*VC)            // 148 floats = 592B, 16B-aligned interleaved pair rows
#define ZSTR 76               // vZ row stride
#define NTX (IMG/TW)          // 8
#define NTY (IMG/TH)          // 32
#define TPP (NTX*NTY)         // 256
#define NBLOCKS (NPLANES*TPP) // 12288
#define NPIX (16.0f*3.0f*512.0f*512.0f)

typedef float v2f __attribute__((ext_vector_type(2)));

// Packed fp32 math (VOP3P, 2 fp32 FMA / instr). Compiler never forms these.
__device__ __forceinline__ v2f pk_fma(v2f a, v2f b, v2f c) {
    v2f d;
    asm("v_pk_fma_f32 %0, %1, %2, %3" : "=v"(d) : "v"(a), "v"(b), "v"(c));
    return d;
}
__device__ __forceinline__ v2f pk_mul(v2f a, v2f b) {
    v2f d;
    asm("v_pk_mul_f32 %0, %1, %2" : "=v"(d) : "v"(a), "v"(b));
    return d;
}

__device__ __forceinline__ float fast_rcp(float d) {
    float r = __builtin_amdgcn_rcpf(d);
    r = r * (2.0f - d * r);   // one Newton step: ~1e-7 rel error
    return r;
}

// LDS budget: raw 2*26*76*4 = 15,808 + v01/v23 2*16*148*4 = 18,944
//           + vZ 16*76*4 = 4,864 + wsum 16  = 39,632 B  -> 4 blocks/CU (158.5KB).
// (256,4): 16 waves/CU, VGPR cap 128 (working set ~110). Watch WRITE_SIZE for spill.
__global__ __launch_bounds__(256, 4) void ssim_kernel(
    const float* __restrict__ img1, const float* __restrict__ img2,
    float* __restrict__ partial)
{
    __shared__ __align__(16) float raw1[RROWS][RSTR];
    __shared__ __align__(16) float raw2[RROWS][RSTR];
    __shared__ __align__(16) float v01[TH][PRW];   // (mu1,mu2) interleaved pairs
    __shared__ __align__(16) float v23[TH][PRW];   // (E[aa],E[bb])
    __shared__ __align__(16) float vZ [TH][ZSTR];  // E[ab]
    __shared__ float wsum[4];

    const float cw[KW] = {
        0.00102838f, 0.00759876f, 0.03600077f, 0.10936069f, 0.21300553f,
        0.26601172f,
        0.21300553f, 0.10936069f, 0.03600077f, 0.00759876f, 0.00102838f
    };
    const v2f cw2[KW] = {
        {0.00102838f,0.00102838f}, {0.00759876f,0.00759876f},
        {0.03600077f,0.03600077f}, {0.10936069f,0.10936069f},
        {0.21300553f,0.21300553f}, {0.26601172f,0.26601172f},
        {0.21300553f,0.21300553f}, {0.10936069f,0.10936069f},
        {0.03600077f,0.03600077f}, {0.00759876f,0.00759876f},
        {0.00102838f,0.00102838f}
    };

    const int tid = threadIdx.x;
    const int blk = blockIdx.x;
    const int plane = blk / TPP;
    const int t     = blk % TPP;
    const int ty0 = (t / NTX) * TH;
    const int tx0 = (t % NTX) * TW;
    const float* __restrict__ p1 = img1 + (size_t)plane * IMG * IMG;
    const float* __restrict__ p2 = img2 + (size_t)plane * IMG * IMG;

    // staged window: cols [tx0-6, tx0+70), rows [ty0-5, ty0+21)
    const bool interior = (tx0 >= 6) && (tx0 + 70 <= IMG) &&
                          (ty0 >= RD) && (ty0 + TH + RD <= IMG);

    // ---- pass 0: stage raw pixels global -> LDS (one vmcnt drain per block) ----
    // 988 float2 granules per image; 2 granule-pairs per thread per iter.
    if (interior) {
        const float* b1 = p1 + (ty0 - RD) * IMG + (tx0 - 6);
        const float* b2 = p2 + (ty0 - RD) * IMG + (tx0 - 6);
        #pragma unroll
        for (int it = 0; it < 4; it++) {
            const int g = tid + it * 256;
            if (g < NGRAN) {
                const int row = g / GPR;
                const int pc  = g - row * GPR;
                const float2 qa = *(const float2*)(b1 + row * IMG + 2 * pc);
                const float2 qb = *(const float2*)(b2 + row * IMG + 2 * pc);
                *(float2*)&raw1[row][2 * pc] = qa;
                *(float2*)&raw2[row][2 * pc] = qb;
            }
        }
    } else {
        #pragma unroll
        for (int it = 0; it < 4; it++) {
            const int g = tid + it * 256;
            if (g < NGRAN) {
                const int row = g / GPR;
                const int pc  = g - row * GPR;
                const int gy  = ty0 - RD + row;
                const int gx  = tx0 - 6 + 2 * pc;    // even; pair never straddles border
                const bool ok = (gy >= 0) && (gy < IMG) && (gx >= 0) && (gx < IMG);
                const int gi  = gy * IMG + gx;
                float2 qa = {0.f, 0.f}, qb = {0.f, 0.f};
                if (ok) {
                    qa = *(const float2*)(p1 + gi);
                    qb = *(const float2*)(p2 + gi);
                }
                *(float2*)&raw1[row][2 * pc] = qa;
                *(float2*)&raw2[row][2 * pc] = qb;
            }
        }
    }
    __syncthreads();

    // ---- pass 1: vertical 11-tap from LDS raw ----
    // 148 tasks = 74 cols x 2 row-segments of 8 outputs; 37 tasks per wave
    // (no wave gets a double-length tail).
    {
        const int wv = tid >> 6, lane = tid & 63;
        if (lane < 37) {
            const int task = wv * 37 + lane;       // 0..147
            const int seg  = task / VC;            // 0..1
            const int c    = task - seg * VC;      // 0..73
            const int r0   = seg * 8;
            const int cc   = c + 1;                // raw col index (gx = tx0+c-5)

            float a[18], b[18];
            #pragma unroll
            for (int k = 0; k < 18; k++) {
                a[k] = raw1[r0 + k][cc];
                b[k] = raw2[r0 + k][cc];
            }

            v2f sAB[8], sXY[8];
            float sZ[8];
            #pragma unroll
            for (int o = 0; o < 8; o++) {
                sAB[o] = (v2f){0.f, 0.f};
                sXY[o] = (v2f){0.f, 0.f};
                sZ[o]  = 0.f;
            }

            #pragma unroll
            for (int k = 0; k < 18; k++) {
                v2f rab; rab.x = a[k]; rab.y = b[k];
                const v2f rxy = pk_mul(rab, rab);   // (aa, bb)
                const float ab = a[k] * b[k];
                #pragma unroll
                for (int o = 0; o < 8; o++) {
                    const int d = k - o;            // tap index, compile-time
                    if (d >= 0 && d < KW) {
                        sAB[o] = pk_fma(cw2[d], rab, sAB[o]);
                        sXY[o] = pk_fma(cw2[d], rxy, sXY[o]);
                        sZ[o]  = fmaf(cw[d], ab, sZ[o]);
                    }
                }
            }

            #pragma unroll
            for (int o = 0; o < 8; o++) {
                const int r = r0 + o;
                *(v2f*)&v01[r][2 * c] = sAB[o];
                *(v2f*)&v23[r][2 * c] = sXY[o];
                vZ[r][c] = sZ[o];
            }
        }
    }
    __syncthreads();

    // ---- pass 2: horizontal 11-tap (packed) + SSIM; exactly 1 task/thread ----
    const float C1 = 1e-4f;
    const float C2 = 9e-4f;
    const v2f NEG1 = {-1.f, -1.f};
    float acc = 0.f;
    {
        const int j = tid & 15;              // group: outputs 4j..4j+3
        const int r = tid >> 4;              // row 0..15

        v2f prAB[14], prXY[14];
        {
            const float4* rowp = (const float4*)&v01[r][0];
            #pragma unroll
            for (int i = 0; i < 7; i++) {
                const float4 q = rowp[2 * j + i];
                prAB[2 * i]     = (v2f){q.x, q.y};
                prAB[2 * i + 1] = (v2f){q.z, q.w};
            }
        }
        {
            const float4* rowp = (const float4*)&v23[r][0];
            #pragma unroll
            for (int i = 0; i < 7; i++) {
                const float4 q = rowp[2 * j + i];
                prXY[2 * i]     = (v2f){q.x, q.y};
                prXY[2 * i + 1] = (v2f){q.z, q.w};
            }
        }
        float zv[16];
        {
            const float4* rowp = (const float4*)&vZ[r][0];
            #pragma unroll
            for (int i = 0; i < 4; i++) {
                const float4 q = rowp[j + i];
                zv[4*i] = q.x; zv[4*i+1] = q.y; zv[4*i+2] = q.z; zv[4*i+3] = q.w;
            }
        }

        #pragma unroll
        for (int o = 0; o < 4; o++) {
            v2f M  = (v2f){0.f, 0.f};   // (mu1, mu2)
            v2f X  = (v2f){0.f, 0.f};   // (E[aa], E[bb])
            float z = 0.f;              // E[ab]
            #pragma unroll
            for (int d = 0; d < KW; d++) {
                M = pk_fma(cw2[d], prAB[o + d], M);
                X = pk_fma(cw2[d], prXY[o + d], X);
                z = fmaf(cw[d], zv[o + d], z);
            }
            const v2f M2 = pk_mul(M, M);           // (mu1^2, mu2^2)
            const v2f S  = pk_fma(M2, NEG1, X);    // (sigma1_sq, sigma2_sq)
            const float mu12 = M.x * M.y;
            const float s12  = z - mu12;
            const float num = fmaf(2.f, mu12, C1) * fmaf(2.f, s12, C2);
            const float den = (M2.x + M2.y + C1) * (S.x + S.y + C2);
            acc += num * fast_rcp(den);
        }
    }

    // ---- block reduction ----
    #pragma unroll
    for (int off = 32; off > 0; off >>= 1)
        acc += __shfl_down(acc, off, 64);
    const int lane = tid & 63;
    const int wv_i = tid >> 6;
    if (lane == 0) wsum[wv_i] = acc;
    __syncthreads();
    if (tid == 0)
        partial[blk] = (wsum[0] + wsum[1]) + (wsum[2] + wsum[3]);
}

__global__ __launch_bounds__(256) void ssim_reduce_kernel(
    const float* __restrict__ partial, float* __restrict__ out)
{
    float acc = 0.f;
    for (int i = threadIdx.x; i < NBLOCKS; i += 256)
        acc += partial[i];
    #pragma unroll
    for (int off = 32; off > 0; off >>= 1)
        acc += __shfl_down(acc, off, 64);
    __shared__ float wsum[4];
    const int lane = threadIdx.x & 63;
    const int wv_i = threadIdx.x >> 6;
    if (lane == 0) wsum[wv_i] = acc;
    __syncthreads();
    if (threadIdx.x == 0)
        out[0] = ((wsum[0] + wsum[1]) + (wsum[2] + wsum[3])) * (1.0f / NPIX);
}

extern "C" void kernel_launch(void* const* d_in, const int* in_sizes, int n_in,
                              void* d_out, int out_size, void* d_ws, size_t ws_size,
                              hipStream_t stream) {
    const float* img1 = (const float*)d_in[0];
    const float* img2 = (const float*)d_in[1];
    float* out = (float*)d_out;
    float* partial = (float*)d_ws;   // NBLOCKS floats (48KB) of scratch

    ssim_kernel<<<NBLOCKS, 256, 0, stream>>>(img1, img2, partial);
    ssim_reduce_kernel<<<1, 256, 0, stream>>>(partial, out);
}

// Round 9
// 146.736 us; speedup vs baseline: 1.2096x; 1.2096x over previous
//
#include <hip/hip_runtime.h>

#define IMG 512
#define NPLANES 48            // 16*3
#define TW 64                 // output tile width
#define TH 32                 // output tile height
#define RD 5
#define KW 11
#define VC (TW + 2*RD)        // 74 columns of vertical sums
#define PRW (2*VC)            // 148 floats = 592B rows (16B-aligned)
#define NTX (IMG/TW)          // 8
#define NTY (IMG/TH)          // 16
#define TPP (NTX*NTY)         // 128
#define NBLOCKS (NPLANES*TPP) // 6144
#define NPIX (16.0f*3.0f*512.0f*512.0f)

typedef float v2f __attribute__((ext_vector_type(2)));

// Packed fp32 math (VOP3P, 2 fp32 ops / instr). Compiler never forms these.
// NOTE (R8 lesson): VOP3P operands must be 64-bit VGPR PAIRS — passing two
// independent scalar floats to an asm "v" pair constraint miscompiles.
__device__ __forceinline__ v2f pk_fma(v2f a, v2f b, v2f c) {
    v2f d;
    asm("v_pk_fma_f32 %0, %1, %2, %3" : "=v"(d) : "v"(a), "v"(b), "v"(c));
    return d;
}
__device__ __forceinline__ v2f pk_mul(v2f a, v2f b) {
    v2f d;
    asm("v_pk_mul_f32 %0, %1, %2" : "=v"(d) : "v"(a), "v"(b));
    return d;
}
// (a+b, a-b) via scalar add/sub; compiler builds the pair for asm consumers.
__device__ __forceinline__ v2f pk_sd(float a, float b) {
    v2f d;
    d.x = a + b;
    d.y = a - b;
    return d;
}

__device__ __forceinline__ float fast_rcp(float d) {
    float r = __builtin_amdgcn_rcpf(d);
    r = r * (2.0f - d * r);   // one Newton step: ~1e-7 rel error
    return r;
}

// (s,d) channel decomposition: s=a+b, d=a-b.
//   mus^2 - mud^2 = 4 mu1 mu2      mus^2 + mud^2 = 2(mu1^2+mu2^2)
//   Vs - Vd       = 4 sigma12      Vs + Vd       = 2(sigma1^2+sigma2^2)
// -> 2 packed conv channels (s,d) and (s^2,d^2) replace the old 5.
// LDS: 2*32*148*4 = 37,888 B -> 4 blocks/CU = 16 waves/CU.
__global__ __launch_bounds__(256) void ssim_kernel(
    const float* __restrict__ img1, const float* __restrict__ img2,
    float* __restrict__ partial)
{
    __shared__ __align__(16) float vSD[TH][PRW];  // (mus, mud) vertical sums
    __shared__ __align__(16) float vQ [TH][PRW];  // (E[ss], E[dd]) vertical sums
    __shared__ float wsum[4];

    const v2f cw2[KW] = {
        {0.00102838f,0.00102838f}, {0.00759876f,0.00759876f},
        {0.03600077f,0.03600077f}, {0.10936069f,0.10936069f},
        {0.21300553f,0.21300553f}, {0.26601172f,0.26601172f},
        {0.21300553f,0.21300553f}, {0.10936069f,0.10936069f},
        {0.03600077f,0.03600077f}, {0.00759876f,0.00759876f},
        {0.00102838f,0.00102838f}
    };

    const int tid = threadIdx.x;
    const int blk = blockIdx.x;
    const int plane = blk / TPP;
    const int t     = blk % TPP;
    const int ty0 = (t / NTX) * TH;
    const int tx0 = (t % NTX) * TW;
    const float* __restrict__ p1 = img1 + (size_t)plane * IMG * IMG;
    const float* __restrict__ p2 = img2 + (size_t)plane * IMG * IMG;

    // block-uniform: no element touches the image border -> skip all predication
    const bool interior = (tx0 >= RD) && (tx0 + TW + RD <= IMG) &&
                          (ty0 >= RD) && (ty0 + TH + RD <= IMG);

    // ---- pass 1: vertical 11-tap on (s,d) and (s^2,d^2), global -> LDS ----
    // 296 tasks: (col 0..73) x (4 row-segments of 8 outputs)
    for (int task = tid; task < VC * 4; task += 256) {
        const int col = task % VC;       // storage column
        const int seg = task / VC;       // 0..3
        const int gx  = tx0 + col - RD;
        const int r0  = seg * 8;

        float a[18], b[18];
        if (interior) {
            // uniform base + 32-bit offset -> saddr-form loads
            const unsigned off0 = (unsigned)((ty0 + r0 - RD) * IMG + gx);
            #pragma unroll
            for (int k = 0; k < 18; k++) {
                a[k] = p1[off0 + (unsigned)(k * IMG)];
                b[k] = p2[off0 + (unsigned)(k * IMG)];
            }
        } else {
            const bool xok = (gx >= 0) && (gx < IMG);
            #pragma unroll
            for (int k = 0; k < 18; k++) {
                const int gy = ty0 + r0 + k - RD;
                const bool ok = xok && (gy >= 0) && (gy < IMG);
                const int gi = gy * IMG + gx;
                a[k] = ok ? p1[gi] : 0.f;
                b[k] = ok ? p2[gi] : 0.f;
            }
        }

        // packed vertical conv: per tap 2 pk_fma; first tap (d==0) is a
        // pk_mul so no accumulator zero-init movs are ever emitted.
        v2f sSD[8], sQ[8];
        #pragma unroll
        for (int k = 0; k < 18; k++) {
            const v2f sd = pk_sd(a[k], b[k]);    // (a+b, a-b)
            const v2f q  = pk_mul(sd, sd);       // (s^2,  d^2)
            #pragma unroll
            for (int o = 0; o < 8; o++) {
                const int d = k - o;             // tap index, compile-time
                if (d == 0) {
                    sSD[o] = pk_mul(cw2[0], sd);
                    sQ[o]  = pk_mul(cw2[0], q);
                } else if (d > 0 && d < KW) {
                    sSD[o] = pk_fma(cw2[d], sd, sSD[o]);
                    sQ[o]  = pk_fma(cw2[d], q,  sQ[o]);
                }
            }
        }

        #pragma unroll
        for (int o = 0; o < 8; o++) {
            const int r = r0 + o;
            *(v2f*)&vSD[r][2 * col] = sSD[o];
            *(v2f*)&vQ [r][2 * col] = sQ[o];
        }
    }
    __syncthreads();

    // ---- pass 2: horizontal 11-tap (packed) + SSIM ----
    const float C1 = 1e-4f;
    const float C2 = 9e-4f;
    const v2f NEG1 = {-1.f, -1.f};
    float acc = 0.f;
    #pragma unroll
    for (int it = 0; it < 2; it++) {
        const int task = tid + it * 256;     // 0..511
        const int j = task & 15;             // group: outputs 4j..4j+3
        const int r = task >> 4;             // row 0..31

        // pairs 4j .. 4j+13 -> exactly 7 float4 reads per array
        v2f prSD[14], prQ[14];
        {
            const float4* rowp = (const float4*)&vSD[r][0];
            #pragma unroll
            for (int i = 0; i < 7; i++) {
                const float4 q = rowp[2 * j + i];
                prSD[2 * i]     = (v2f){q.x, q.y};
                prSD[2 * i + 1] = (v2f){q.z, q.w};
            }
        }
        {
            const float4* rowp = (const float4*)&vQ[r][0];
            #pragma unroll
            for (int i = 0; i < 7; i++) {
                const float4 q = rowp[2 * j + i];
                prQ[2 * i]     = (v2f){q.x, q.y};
                prQ[2 * i + 1] = (v2f){q.z, q.w};
            }
        }

        #pragma unroll
        for (int o = 0; o < 4; o++) {
            v2f M = pk_mul(cw2[0], prSD[o]);   // (mus, mud)
            v2f X = pk_mul(cw2[0], prQ[o]);    // (E[ss], E[dd])
            #pragma unroll
            for (int d = 1; d < KW; d++) {
                M = pk_fma(cw2[d], prSD[o + d], M);
                X = pk_fma(cw2[d], prQ[o + d], X);
            }
            const v2f M2 = pk_mul(M, M);          // (mus^2, mud^2)
            const v2f V  = pk_fma(M2, NEG1, X);   // (Vs, Vd)
            const float mm = M2.x - M2.y;         // 4 mu1 mu2
            const float mp = M2.x + M2.y;         // 2 (mu1^2 + mu2^2)
            const float vm = V.x - V.y;           // 4 sigma12
            const float vp = V.x + V.y;           // 2 (s1^2 + s2^2)
            const float num = fmaf(0.5f, mm, C1) * fmaf(0.5f, vm, C2);
            const float den = fmaf(0.5f, mp, C1) * fmaf(0.5f, vp, C2);
            acc += num * fast_rcp(den);
        }
    }

    // ---- block reduction ----
    #pragma unroll
    for (int off = 32; off > 0; off >>= 1)
        acc += __shfl_down(acc, off, 64);
    const int lane = tid & 63;
    const int wv_i = tid >> 6;
    if (lane == 0) wsum[wv_i] = acc;
    __syncthreads();
    if (tid == 0)
        partial[blk] = (wsum[0] + wsum[1]) + (wsum[2] + wsum[3]);
}

__global__ __launch_bounds__(256) void ssim_reduce_kernel(
    const float* __restrict__ partial, float* __restrict__ out)
{
    float acc = 0.f;
    for (int i = threadIdx.x; i < NBLOCKS; i += 256)
        acc += partial[i];
    #pragma unroll
    for (int off = 32; off > 0; off >>= 1)
        acc += __shfl_down(acc, off, 64);
    __shared__ float wsum[4];
    const int lane = threadIdx.x & 63;
    const int wv_i = threadIdx.x >> 6;
    if (lane == 0) wsum[wv_i] = acc;
    __syncthreads();
    if (threadIdx.x == 0)
        out[0] = ((wsum[0] + wsum[1]) + (wsum[2] + wsum[3])) * (1.0f / NPIX);
}

extern "C" void kernel_launch(void* const* d_in, const int* in_sizes, int n_in,
                              void* d_out, int out_size, void* d_ws, size_t ws_size,
                              hipStream_t stream) {
    const float* img1 = (const float*)d_in[0];
    const float* img2 = (const float*)d_in[1];
    float* out = (float*)d_out;
    float* partial = (float*)d_ws;   // NBLOCKS floats of scratch

    ssim_kernel<<<NBLOCKS, 256, 0, stream>>>(img1, img2, partial);
    ssim_reduce_kernel<<<1, 256, 0, stream>>>(partial, out);
}

// Round 10
// 146.379 us; speedup vs baseline: 1.2125x; 1.0024x over previous
//
#include <hip/hip_runtime.h>

#define IMG 512
#define NPLANES 48            // 16*3
#define TW 64                 // output tile width
#define TH 32                 // output tile height
#define RD 5
#define KW 11
#define VC (TW + 2*RD)        // 74 columns of vertical sums
#define PRW (2*VC)            // 148 floats = 592B rows (16B-aligned)
#define NTX (IMG/TW)          // 8
#define NTY (IMG/TH)          // 16
#define TPP (NTX*NTY)         // 128
#define NBLOCKS (NPLANES*TPP) // 6144
#define NPIX (16.0f*3.0f*512.0f*512.0f)

typedef float v2f __attribute__((ext_vector_type(2)));

// Packed fp32 math (VOP3P, 2 fp32 ops / instr). Compiler never forms these.
// VOP3P asm operands must be 64-bit VGPR PAIRS (R8 lesson).
__device__ __forceinline__ v2f pk_fma(v2f a, v2f b, v2f c) {
    v2f d;
    asm("v_pk_fma_f32 %0, %1, %2, %3" : "=v"(d) : "v"(a), "v"(b), "v"(c));
    return d;
}
__device__ __forceinline__ v2f pk_mul(v2f a, v2f b) {
    v2f d;
    asm("v_pk_mul_f32 %0, %1, %2" : "=v"(d) : "v"(a), "v"(b));
    return d;
}
// (a+b, a-b) via scalar add/sub; compiler builds the pair for asm consumers.
__device__ __forceinline__ v2f pk_sd(float a, float b) {
    v2f d;
    d.x = a + b;
    d.y = a - b;
    return d;
}

__device__ __forceinline__ float fast_rcp(float d) {
    float r = __builtin_amdgcn_rcpf(d);
    r = r * (2.0f - d * r);   // one Newton step: ~1e-7 rel error
    return r;
}

// (s,d) channel decomposition: s=a+b, d=a-b.
//   mus^2 - mud^2 = 4 mu1 mu2      mus^2 + mud^2 = 2(mu1^2+mu2^2)
//   Vs - Vd       = 4 sigma12      Vs + Vd       = 2(sigma1^2+sigma2^2)
// R10: 16-output pass-1 tasks (halo rows loaded once per 16 outputs, not per 8)
//      and 8-output pass-2 tasks (halo pairs read once per 8 outputs, not per 4).
// LDS: 2*32*148*4 = 37,888 B -> 4 blocks/CU = 16 waves/CU.
__global__ __launch_bounds__(256) void ssim_kernel(
    const float* __restrict__ img1, const float* __restrict__ img2,
    float* __restrict__ partial)
{
    __shared__ __align__(16) float vSD[TH][PRW];  // (mus, mud) vertical sums
    __shared__ __align__(16) float vQ [TH][PRW];  // (E[ss], E[dd]) vertical sums
    __shared__ float wsum[4];

    const v2f cw2[KW] = {
        {0.00102838f,0.00102838f}, {0.00759876f,0.00759876f},
        {0.03600077f,0.03600077f}, {0.10936069f,0.10936069f},
        {0.21300553f,0.21300553f}, {0.26601172f,0.26601172f},
        {0.21300553f,0.21300553f}, {0.10936069f,0.10936069f},
        {0.03600077f,0.03600077f}, {0.00759876f,0.00759876f},
        {0.00102838f,0.00102838f}
    };

    const int tid = threadIdx.x;
    const int blk = blockIdx.x;
    const int plane = blk / TPP;
    const int t     = blk % TPP;
    const int ty0 = (t / NTX) * TH;
    const int tx0 = (t % NTX) * TW;
    const float* __restrict__ p1 = img1 + (size_t)plane * IMG * IMG;
    const float* __restrict__ p2 = img2 + (size_t)plane * IMG * IMG;

    // block-uniform: no element touches the image border -> skip all predication
    const bool interior = (tx0 >= RD) && (tx0 + TW + RD <= IMG) &&
                          (ty0 >= RD) && (ty0 + TH + RD <= IMG);

    // ---- pass 1: vertical 11-tap on (s,d) and (s^2,d^2), global -> LDS ----
    // 148 tasks: (col 0..73) x (2 segment-pairs of 16 outputs); single round.
    if (tid < VC * 2) {
        const int col = tid % VC;        // storage column
        const int sp  = tid / VC;        // 0..1
        const int gx  = tx0 + col - RD;
        const int r0  = sp * 16;

        float a[26], b[26];
        if (interior) {
            // uniform base + 32-bit offset -> saddr-form loads
            const unsigned off0 = (unsigned)((ty0 + r0 - RD) * IMG + gx);
            #pragma unroll
            for (int k = 0; k < 26; k++) {
                a[k] = p1[off0 + (unsigned)(k * IMG)];
                b[k] = p2[off0 + (unsigned)(k * IMG)];
            }
        } else {
            const bool xok = (gx >= 0) && (gx < IMG);
            #pragma unroll
            for (int k = 0; k < 26; k++) {
                const int gy = ty0 + r0 + k - RD;
                const bool ok = xok && (gy >= 0) && (gy < IMG);
                const int gi = gy * IMG + gx;
                a[k] = ok ? p1[gi] : 0.f;
                b[k] = ok ? p2[gi] : 0.f;
            }
        }

        // packed vertical conv: per tap 2 pk_fma; first tap (d==0) is a
        // pk_mul so no accumulator zero-init movs are ever emitted.
        // Same per-output tap order (d ascending) as R9 -> bit-identical.
        v2f sSD[16], sQ[16];
        #pragma unroll
        for (int k = 0; k < 26; k++) {
            const v2f sd = pk_sd(a[k], b[k]);    // (a+b, a-b)
            const v2f q  = pk_mul(sd, sd);       // (s^2,  d^2)
            #pragma unroll
            for (int o = 0; o < 16; o++) {
                const int d = k - o;             // tap index, compile-time
                if (d == 0) {
                    sSD[o] = pk_mul(cw2[0], sd);
                    sQ[o]  = pk_mul(cw2[0], q);
                } else if (d > 0 && d < KW) {
                    sSD[o] = pk_fma(cw2[d], sd, sSD[o]);
                    sQ[o]  = pk_fma(cw2[d], q,  sQ[o]);
                }
            }
        }

        #pragma unroll
        for (int o = 0; o < 16; o++) {
            const int r = r0 + o;
            *(v2f*)&vSD[r][2 * col] = sSD[o];
            *(v2f*)&vQ [r][2 * col] = sQ[o];
        }
    }
    __syncthreads();

    // ---- pass 2: horizontal 11-tap (packed) + SSIM; 8 outputs/thread ----
    const float C1 = 1e-4f;
    const float C2 = 9e-4f;
    const v2f NEG1 = {-1.f, -1.f};
    float acc = 0.f;
    {
        const int j = tid & 7;               // group: outputs 8j..8j+7
        const int r = tid >> 3;              // row 0..31

        // pairs 8j .. 8j+17 -> exactly 9 float4 reads per array
        v2f prSD[18], prQ[18];
        {
            const float4* rowp = (const float4*)&vSD[r][0];
            #pragma unroll
            for (int i = 0; i < 9; i++) {
                const float4 q = rowp[4 * j + i];
                prSD[2 * i]     = (v2f){q.x, q.y};
                prSD[2 * i + 1] = (v2f){q.z, q.w};
            }
        }
        {
            const float4* rowp = (const float4*)&vQ[r][0];
            #pragma unroll
            for (int i = 0; i < 9; i++) {
                const float4 q = rowp[4 * j + i];
                prQ[2 * i]     = (v2f){q.x, q.y};
                prQ[2 * i + 1] = (v2f){q.z, q.w};
            }
        }

        #pragma unroll
        for (int o = 0; o < 8; o++) {
            v2f M = pk_mul(cw2[0], prSD[o]);   // (mus, mud)
            v2f X = pk_mul(cw2[0], prQ[o]);    // (E[ss], E[dd])
            #pragma unroll
            for (int d = 1; d < KW; d++) {
                M = pk_fma(cw2[d], prSD[o + d], M);
                X = pk_fma(cw2[d], prQ[o + d], X);
            }
            const v2f M2 = pk_mul(M, M);          // (mus^2, mud^2)
            const v2f V  = pk_fma(M2, NEG1, X);   // (Vs, Vd)
            const float mm = M2.x - M2.y;         // 4 mu1 mu2
            const float mp = M2.x + M2.y;         // 2 (mu1^2 + mu2^2)
            const float vm = V.x - V.y;           // 4 sigma12
            const float vp = V.x + V.y;           // 2 (s1^2 + s2^2)
            const float num = fmaf(0.5f, mm, C1) * fmaf(0.5f, vm, C2);
            const float den = fmaf(0.5f, mp, C1) * fmaf(0.5f, vp, C2);
            acc += num * fast_rcp(den);
        }
    }

    // ---- block reduction ----
    #pragma unroll
    for (int off = 32; off > 0; off >>= 1)
        acc += __shfl_down(acc, off, 64);
    const int lane = tid & 63;
    const int wv_i = tid >> 6;
    if (lane == 0) wsum[wv_i] = acc;
    __syncthreads();
    if (tid == 0)
        partial[blk] = (wsum[0] + wsum[1]) + (wsum[2] + wsum[3]);
}

__global__ __launch_bounds__(256) void ssim_reduce_kernel(
    const float* __restrict__ partial, float* __restrict__ out)
{
    float acc = 0.f;
    for (int i = threadIdx.x; i < NBLOCKS; i += 256)
        acc += partial[i];
    #pragma unroll
    for (int off = 32; off > 0; off >>= 1)
        acc += __shfl_down(acc, off, 64);
    __shared__ float wsum[4];
    const int lane = threadIdx.x & 63;
    const int wv_i = threadIdx.x >> 6;
    if (lane == 0) wsum[wv_i] = acc;
    __syncthreads();
    if (threadIdx.x == 0)
        out[0] = ((wsum[0] + wsum[1]) + (wsum[2] + wsum[3])) * (1.0f / NPIX);
}

extern "C" void kernel_launch(void* const* d_in, const int* in_sizes, int n_in,
                              void* d_out, int out_size, void* d_ws, size_t ws_size,
                              hipStream_t stream) {
    const float* img1 = (const float*)d_in[0];
    const float* img2 = (const float*)d_in[1];
    float* out = (float*)d_out;
    float* partial = (float*)d_ws;   // NBLOCKS floats of scratch

    ssim_kernel<<<NBLOCKS, 256, 0, stream>>>(img1, img2, partial);
    ssim_reduce_kernel<<<1, 256, 0, stream>>>(partial, out);
}